// Round 2
// baseline (193.933 us; speedup 1.0000x reference)
//
#include <hip/hip_runtime.h>
#include <math.h>

#define BB 8
#define TT 2048
#define EE 1024
#define DD 128

typedef _Float16 f16x8 __attribute__((ext_vector_type(8)));
typedef _Float16 f16x4 __attribute__((ext_vector_type(4)));
typedef float    f32x4 __attribute__((ext_vector_type(4)));
typedef float    f32x16 __attribute__((ext_vector_type(16)));

// scale (128^-0.5) * log2(e): folded into q so softmax runs in exp2 domain
#define QSCALE 0.12752406f

// async global->LDS, 16B per lane; LDS dest = wave-uniform base + lane*16
__device__ __forceinline__ void gl_lds16(const _Float16* g, _Float16* l)
{
    __builtin_amdgcn_global_load_lds(
        (const __attribute__((address_space(1))) void*)g,
        (__attribute__((address_space(3))) void*)l, 16, 0, 0);
}

// ---------------------------------------------------------------------------
// Fragment layouts (32x32x16 MFMA, m74/m101 verified):
//   A[m = lane&31][k = (lane>>5)*8 + j]   (f16x8 per lane)
//   B[k = (lane>>5)*8 + j][n = lane&31]
//   C/D row = (rg&3) + 8*(rg>>2) + 4*(lane>>5), col = lane&31
// Frag-order global arrays: frag_id*512 + lane*8 + j -> 1KB coalesced blobs.
// ---------------------------------------------------------------------------

// Kernel 0: Wb[(kc*12 + ns)*512 + lane*8 + j] = W[k=kc*16+(lane>>5)*8+j][n]
__global__ __launch_bounds__(256)
void wt_prep_kernel(const float* __restrict__ Wq,
                    const float* __restrict__ Wk,
                    const float* __restrict__ Wv,
                    _Float16* __restrict__ Wb)
{
    int gid = blockIdx.x * 256 + threadIdx.x;   // 0..49151
    int kc  = gid / 768;
    int rem = gid - kc * 768;
    int ns  = rem >> 6;
    int ln  = rem & 63;
    int n   = ns * 32 + (ln & 31);
    int k0  = kc * 16 + (ln >> 5) * 8;
    const float* __restrict__ W = (n < 128) ? Wq : (n < 256) ? Wk : Wv;
    int nl = n & 127;
    f16x8 w;
#pragma unroll
    for (int j = 0; j < 8; j++)
        w[j] = (_Float16)W[(size_t)(k0 + j) * DD + nl];
    *(f16x8*)&Wb[(size_t)gid * 8] = w;
}

// ---------------------------------------------------------------------------
// Kernel 1: fused QKV projection.  M=32, N=384, grid 512, 512 thr = 8 waves:
// wave_k (2, K-split halves) x wave_n (4, 3 n-subtiles each).
// 16 waves/CU (4/SIMD) for latency hiding; __launch_bounds__(512,4).
// X: LDS double-buffered A-frag blobs, ONE barrier/iter, 3-deep prefetch ring.
// W: direct frag-order loads from L2-resident Wb (disjoint per wave, batched).
// Epilogue: cross-wave f32 reduce in LDS, all-thread RoPE, frag-order stores.
// ---------------------------------------------------------------------------
__global__ __launch_bounds__(512, 4)
void proj_rope_kernel(const float* __restrict__ x,
                      const _Float16* __restrict__ Wb,
                      _Float16* __restrict__ Qb,
                      _Float16* __restrict__ Ka,
                      _Float16* __restrict__ Va)
{
    const int r0   = blockIdx.x * 32;       // 32 | 2048: never straddles batch
    const int tid  = threadIdx.x;
    const int wave = tid >> 6;              // 0..7
    const int lane = tid & 63;
    const int half = lane >> 5;
    const int col  = lane & 31;
    const int wave_n = wave & 3;
    const int wave_k = wave >> 2;

    __shared__ _Float16 Xb[2][2048];        // 4 blobs (kc) x 512 f16 per buf
    __shared__ float    Fb[2][32][128];     // per-wave_k partial C (one p-slab)
    __shared__ _Float16 Out[32][136];       // store-transpose buffer

    f32x16 acc[3];
#pragma unroll
    for (int s = 0; s < 3; s++) acc[s] = (f32x16)0.f;

    // staging map: 512 thr x 1 float4: row sr, f16-cols sc..sc+3
    const int sr = tid >> 4;                // 0..31
    const int sc = (tid & 15) * 4;          // 0..60
    const float* __restrict__ xp = &x[(size_t)(r0 + sr) * EE + sc];
    // blob index for col c: (c>>4)*512 + (sr + 32*((c>>3)&1))*8 + (c&7)
    const int w0 = ((sc >> 4) << 9) + ((sr + 32 * ((sc >> 3) & 1)) << 3) + (sc & 7);

    // 3-deep prefetch ring: iter0 committed pre-loop; na=iter1, nb=iter2
    float4 pa = *(const float4*)(xp);
    {
        f16x4 h = { (_Float16)pa.x, (_Float16)pa.y, (_Float16)pa.z, (_Float16)pa.w };
        *(f16x4*)&Xb[0][w0] = h;
    }
    float4 na = *(const float4*)(xp + 64);
    float4 nb = *(const float4*)(xp + 128);

    for (int it = 0; it < 16; it++) {
        const int buf = it & 1;
        __syncthreads();                    // Xb[buf] commits visible
        f16x8 a[2], b[6];
#pragma unroll
        for (int kl = 0; kl < 2; kl++)
            a[kl] = *(f16x8*)&Xb[buf][((wave_k * 2 + kl) << 9) + lane * 8];
#pragma unroll
        for (int kl = 0; kl < 2; kl++)
#pragma unroll
            for (int s = 0; s < 3; s++)
                b[kl * 3 + s] = *(const f16x8*)&Wb[((size_t)(it * 4 + wave_k * 2 + kl) * 12 + wave_n * 3 + s) * 512 + lane * 8];
#pragma unroll
        for (int kl = 0; kl < 2; kl++)
#pragma unroll
            for (int s = 0; s < 3; s++)
                acc[s] = __builtin_amdgcn_mfma_f32_32x32x16_f16(a[kl], b[kl * 3 + s], acc[s], 0, 0, 0);
        if (it + 1 < 16) {                  // commit iter it+1 (readers done)
            f16x4 h = { (_Float16)na.x, (_Float16)na.y, (_Float16)na.z, (_Float16)na.w };
            *(f16x4*)&Xb[buf ^ 1][w0] = h;
            na = nb;
        }
        if (it + 3 < 16)                    // issue iter it+3 load
            nb = *(const float4*)(xp + (it + 3) * 64);
    }

    // ---- epilogue: K-split reduce + RoPE + frag-layout stores ----
    const int bidx = r0 >> 11;
    const int t0   = r0 & (TT - 1);

    for (int p = 0; p < 3; p++) {
        __syncthreads();                    // Fb/Out free for this p
        // phase A: both wave_k halves dump partials for this 128-col slab
#pragma unroll
        for (int s = 0; s < 3; s++) {
            int gs = wave_n * 3 + s;        // global 32-col subtile 0..11
            if ((gs >> 2) != p) continue;
            int dcol = (gs & 3) * 32 + col;
#pragma unroll
            for (int rg = 0; rg < 16; rg++) {
                int mrow = (rg & 3) + 8 * (rg >> 2) + 4 * half;
                Fb[wave_k][mrow][dcol] = acc[s][rg];
            }
        }
        __syncthreads();
        // phase B: all 512 threads reduce + (RoPE | cvt) -> Out
        if (p < 2) {
#pragma unroll
            for (int q = 0; q < 4; q++) {
                int pid = tid * 4 + q;      // 0..2047 = 32 rows x 64 pairs
                int row = pid >> 6;
                int cp  = pid & 63;
                float v0 = Fb[0][row][2 * cp]     + Fb[1][row][2 * cp];
                float v1 = Fb[0][row][2 * cp + 1] + Fb[1][row][2 * cp + 1];
                float f  = __powf(10000.0f, -(float)(2 * cp) * (1.0f / 128.0f));
                float sa, ca;
                __sincosf((float)(t0 + row) * f, &sa, &ca);
                float e0 = v0 * ca - v1 * sa;
                float e1 = v0 * sa + v1 * ca;
                if (p == 0) { e0 *= QSCALE; e1 *= QSCALE; }
                Out[row][2 * cp]     = (_Float16)e0;
                Out[row][2 * cp + 1] = (_Float16)e1;
            }
        } else {
#pragma unroll
            for (int q = 0; q < 8; q++) {
                int eid = tid * 8 + q;      // 0..4095
                int row = eid >> 7, cc = eid & 127;
                Out[row][cc] = (_Float16)(Fb[0][row][cc] + Fb[1][row][cc]);
            }
        }
        __syncthreads();
        // phase C: frag-order stores (512 work items)
        if (p < 2) {
            _Float16* __restrict__ dst = (p == 0) ? Qb : Ka;
            int kc = tid >> 6, ln = tid & 63;
            f16x8 v8 = *(f16x8*)&Out[ln & 31][kc * 16 + (ln >> 5) * 8];
            size_t ga = ((((size_t)bidx * 64 + (t0 >> 5)) * 8 + kc) * 64 + ln) * 8;
            *(f16x8*)&dst[ga] = v8;
        } else {
            int kcl = tid >> 8, ds = (tid >> 6) & 3, ln = tid & 63;
            f16x8 vv;
#pragma unroll
            for (int e = 0; e < 8; e++)
                vv[e] = Out[kcl * 16 + (ln >> 5) * 8 + e][ds * 32 + (ln & 31)];
            size_t ga = ((((size_t)bidx * 128 + (t0 >> 4) + kcl) * 4 + ds) * 64 + ln) * 8;
            *(f16x8*)&Va[ga] = vv;
        }
    }
}

// ---------------------------------------------------------------------------
// Kernel 2: MFMA flash attention.  Q-tile 128 (4 waves), K-tile 64, split-K
// chunks of exactly 2 tiles -> grid (136, 8), perfectly uniform work.
// K/V staged single-buffered via global_load_lds (no VGPR round-trip);
// __launch_bounds__(256,3) -> 3 blocks/CU = 12 waves/CU cover the DMA wait.
// ---------------------------------------------------------------------------
__global__ __launch_bounds__(256, 3)
void attn_kernel(const _Float16* __restrict__ Qb,
                 const _Float16* __restrict__ Ka,
                 const _Float16* __restrict__ Va,
                 _Float16* __restrict__ opart,
                 float* __restrict__ mpart,
                 float* __restrict__ lpart)
{
    const int b = blockIdx.y;
    // triangular inversion: v = xt(xt+1)/2 + c, c in [0, xt]
    int xt = 15, c = 0;
    {
        int v = blockIdx.x, s0 = 0;
        for (int j = 0; j < 16; j++) {
            if (v < s0 + j + 1) { xt = j; c = v - s0; break; }
            s0 += j + 1;
        }
    }
    const int q0  = xt * 128;
    const int kt0 = 2 * c;                  // this block's 2 key-tiles

    const int tid  = threadIdx.x;
    const int wave = tid >> 6;
    const int lane = tid & 63;
    const int half = lane >> 5;
    const int col  = lane & 31;

    __shared__ _Float16 Kb[8192];           // 16 blobs (g*8+kc) x 512 f16
    __shared__ _Float16 Vb[8192];           // 16 blobs (kcl*4+ds) x 512 f16
    __shared__ _Float16 Ps[4][32][72];      // [wave][q][key] — same-wave only

    const _Float16* __restrict__ kst = Ka + (size_t)b * 64 * 4096;
    const _Float16* __restrict__ vst = Va + (size_t)b * 128 * 2048;

    const int qg = q0 + wave * 32 + col;    // this lane's query
    f16x8 qb[8];
#pragma unroll
    for (int kc = 0; kc < 8; kc++)
        qb[kc] = *(const f16x8*)&Qb[((((size_t)b * 64 + xt * 4 + wave) * 8 + kc) * 64 + lane) * 8];

    f32x16 Of[4];
#pragma unroll
    for (int t = 0; t < 4; t++) Of[t] = (f32x16)0.f;
    float m_ = -1e30f, l_ = 0.f;

    // async-stage first tile (16KB K + 16KB V, linear blobs)
    {
        const _Float16* kp = kst + (size_t)kt0 * 8192 + (size_t)tid * 8;
        const _Float16* vp = vst + (size_t)kt0 * 8192 + (size_t)tid * 8;
#pragma unroll
        for (int i = 0; i < 4; i++) {
            gl_lds16(kp + (size_t)i * 2048, &Kb[(wave * 64 + i * 256) * 8]);
            gl_lds16(vp + (size_t)i * 2048, &Vb[(wave * 64 + i * 256) * 8]);
        }
    }

#pragma unroll
    for (int tt = 0; tt < 2; tt++) {
        const int kt  = kt0 + tt;
        const int kb0 = kt * 64;
        asm volatile("s_waitcnt vmcnt(0)" ::: "memory");
        __syncthreads();                    // staged tile visible to all waves

        // ---- S^T = K Q^T : rows = keys, cols = queries ----
        f32x16 sf[2];
#pragma unroll
        for (int g = 0; g < 2; g++) {
            sf[g] = (f32x16)0.f;
#pragma unroll
            for (int kc = 0; kc < 8; kc++) {
                f16x8 kf = *(f16x8*)&Kb[((g * 8 + kc) * 64 + lane) * 8];
                sf[g] = __builtin_amdgcn_mfma_f32_32x32x16_f16(kf, qb[kc], sf[g], 0, 0, 0);
            }
        }

        // ---- softmax: 32 key-scores in-lane, one shfl step (xor 32) ----
        const bool diag = (kt >= 2 * xt);
        float mloc = -1e30f;
#pragma unroll
        for (int g = 0; g < 2; g++)
#pragma unroll
            for (int rg = 0; rg < 16; rg++) {
                int key = kb0 + g * 32 + (rg & 3) + 8 * (rg >> 2) + 4 * half;
                float val = sf[g][rg];
                val = (!diag || key <= qg) ? val : -1e30f;
                sf[g][rg] = val;
                mloc = fmaxf(mloc, val);
            }
        mloc = fmaxf(mloc, __shfl_xor(mloc, 32));
        float mnew  = fmaxf(m_, mloc);
        float alpha = __builtin_amdgcn_exp2f(m_ - mnew);
        float ps = 0.f;
#pragma unroll
        for (int g = 0; g < 2; g++) {
#pragma unroll
            for (int rc = 0; rc < 4; rc++) {
                f16x4 p4;
#pragma unroll
                for (int rr = 0; rr < 4; rr++) {
                    float p = __builtin_amdgcn_exp2f(sf[g][4 * rc + rr] - mnew);
                    ps += p;
                    p4[rr] = (_Float16)p;
                }
                *(f16x4*)&Ps[wave][col][g * 32 + 8 * rc + 4 * half] = p4;
            }
        }
        ps += __shfl_xor(ps, 32);
        l_ = l_ * alpha + ps;
        m_ = mnew;
#pragma unroll
        for (int t = 0; t < 4; t++) Of[t] *= alpha;

        // ---- O^T += V^T P^T (P via same-wave LDS round-trip) ----
        f16x8 pb[4];
#pragma unroll
        for (int kc = 0; kc < 4; kc++)
            pb[kc] = *(f16x8*)&Ps[wave][col][kc * 16 + half * 8];
#pragma unroll
        for (int t = 0; t < 4; t++) {
#pragma unroll
            for (int kcl = 0; kcl < 4; kcl++) {
                f16x8 vf = *(f16x8*)&Vb[((kcl * 4 + t) * 64 + lane) * 8];
                Of[t] = __builtin_amdgcn_mfma_f32_32x32x16_f16(vf, pb[kcl], Of[t], 0, 0, 0);
            }
        }

        if (tt == 0) {
            __syncthreads();                // all waves done reading tile 0
            const _Float16* kp = kst + (size_t)(kt0 + 1) * 8192 + (size_t)tid * 8;
            const _Float16* vp = vst + (size_t)(kt0 + 1) * 8192 + (size_t)tid * 8;
#pragma unroll
            for (int i = 0; i < 4; i++) {
                gl_lds16(kp + (size_t)i * 2048, &Kb[(wave * 64 + i * 256) * 8]);
                gl_lds16(vp + (size_t)i * 2048, &Vb[(wave * 64 + i * 256) * 8]);
            }
        }
    }

    // ---- partial store (f16 unnormalized O^T -> [q][d], f32 m/l) ----
    const int slot = (b * 16 + xt) * 16 + c;
    _Float16* op = opart + ((size_t)slot * 128 + wave * 32 + col) * DD;
#pragma unroll
    for (int t = 0; t < 4; t++) {
#pragma unroll
        for (int rc = 0; rc < 4; rc++) {
            f16x4 o4 = { (_Float16)Of[t][4 * rc + 0], (_Float16)Of[t][4 * rc + 1],
                         (_Float16)Of[t][4 * rc + 2], (_Float16)Of[t][4 * rc + 3] };
            *(f16x4*)&op[t * 32 + 8 * rc + 4 * half] = o4;
        }
    }
    if (half == 0) {
        mpart[slot * 128 + wave * 32 + col] = m_;
        lpart[slot * 128 + wave * 32 + col] = l_;
    }
}

// ---------------------------------------------------------------------------
// Kernel 3: combine up to 16 split-K partials per query row.
// ---------------------------------------------------------------------------
__global__ __launch_bounds__(256)
void combine_kernel(const _Float16* __restrict__ opart,
                    const float* __restrict__ mpart,
                    const float* __restrict__ lpart,
                    float* __restrict__ out)
{
    int gid = blockIdx.x * 256 + threadIdx.x;   // 0..2M-1
    int d   = gid & 127;
    int t   = gid >> 7;                         // 0..16383
    int b   = t >> 11;
    int tl  = t & (TT - 1);
    int xt  = tl >> 7;
    int rl  = tl & 127;
    int np  = xt + 1;                           // chunks of 2 tiles each
    int sb  = (b * 16 + xt) * 16;

    float mm = -1e30f;
    for (int j = 0; j < np; j++)
        mm = fmaxf(mm, mpart[(sb + j) * 128 + rl]);
    float acc = 0.f, den = 0.f;
    for (int j = 0; j < np; j++) {
        float w = __builtin_amdgcn_exp2f(mpart[(sb + j) * 128 + rl] - mm);
        den += w * lpart[(sb + j) * 128 + rl];
        acc += w * (float)opart[((size_t)(sb + j) * 128 + rl) * DD + d];
    }
    out[gid] = acc / den;
}

extern "C" void kernel_launch(void* const* d_in, const int* in_sizes, int n_in,
                              void* d_out, int out_size, void* d_ws, size_t ws_size,
                              hipStream_t stream)
{
    const float* x  = (const float*)d_in[0];
    const float* Wq = (const float*)d_in[1];
    const float* Wk = (const float*)d_in[2];
    const float* Wv = (const float*)d_in[3];
    float* out = (float*)d_out;

    const size_t NTOK = (size_t)BB * TT;        // 16384
    _Float16* Qb = (_Float16*)d_ws;             // 4 MB
    _Float16* Ka = Qb + NTOK * DD;              // 4 MB
    _Float16* Va = Ka + NTOK * DD;              // 4 MB
    _Float16* Wb = Va + NTOK * DD;              // 0.75 MB
    _Float16* opart = Wb + (size_t)384 * EE;    // 64 MB (2048 slots x 128 x 128)
    float* mp = (float*)(opart + (size_t)2048 * 128 * DD);  // 1 MB
    float* lp = mp + 2048 * 128;                // 1 MB

    wt_prep_kernel<<<dim3(192), dim3(256), 0, stream>>>(Wq, Wk, Wv, Wb);
    proj_rope_kernel<<<dim3(512), dim3(512), 0, stream>>>(x, Wb, Qb, Ka, Va);
    attn_kernel<<<dim3(136, BB), dim3(256), 0, stream>>>(Qb, Ka, Va, opart, mp, lp);
    combine_kernel<<<dim3((int)(NTOK * DD / 256)), dim3(256), 0, stream>>>(opart, mp, lp, out);
}

// Round 4
// 188.588 us; speedup vs baseline: 1.0283x; 1.0283x over previous
//
#include <hip/hip_runtime.h>
#include <math.h>

#define BB 8
#define TT 2048
#define EE 1024
#define DD 128

typedef _Float16 f16x8 __attribute__((ext_vector_type(8)));
typedef _Float16 f16x4 __attribute__((ext_vector_type(4)));
typedef float    f32x4 __attribute__((ext_vector_type(4)));
typedef float    f32x16 __attribute__((ext_vector_type(16)));

// scale (128^-0.5) * log2(e): folded into q so softmax runs in exp2 domain
#define QSCALE 0.12752406f

// barrier that does NOT drain vmcnt: LDS correctness needs lgkmcnt only.
// Thread-private global prefetch loads stay in flight across it.
#define BAR_LGKM() asm volatile("s_waitcnt lgkmcnt(0)\n\ts_barrier" ::: "memory")

// ---------------------------------------------------------------------------
// Fragment layouts (32x32x16 MFMA, m74/m101 verified):
//   A[m = lane&31][k = (lane>>5)*8 + j]   (f16x8 per lane)
//   B[k = (lane>>5)*8 + j][n = lane&31]
//   C/D row = (rg&3) + 8*(rg>>2) + 4*(lane>>5), col = lane&31
// Frag-order global arrays: frag_id*512 + lane*8 + j -> 1KB coalesced blobs.
// ---------------------------------------------------------------------------

// Kernel 0: Wb[(kc*12 + ns)*512 + lane*8 + j] = W[k=kc*16+(lane>>5)*8+j][n]
__global__ __launch_bounds__(256)
void wt_prep_kernel(const float* __restrict__ Wq,
                    const float* __restrict__ Wk,
                    const float* __restrict__ Wv,
                    _Float16* __restrict__ Wb)
{
    int gid = blockIdx.x * 256 + threadIdx.x;   // 0..49151
    int kc  = gid / 768;
    int rem = gid - kc * 768;
    int ns  = rem >> 6;
    int ln  = rem & 63;
    int n   = ns * 32 + (ln & 31);
    int k0  = kc * 16 + (ln >> 5) * 8;
    const float* __restrict__ W = (n < 128) ? Wq : (n < 256) ? Wk : Wv;
    int nl = n & 127;
    f16x8 w;
#pragma unroll
    for (int j = 0; j < 8; j++)
        w[j] = (_Float16)W[(size_t)(k0 + j) * DD + nl];
    *(f16x8*)&Wb[(size_t)gid * 8] = w;
}

// ---------------------------------------------------------------------------
// Kernel 1: fused QKV projection.  M=32, N=384, BK=64 (16 iters), grid 512,
// 256 thr = 4 waves (wave_n, 3 n-subtiles each = 32x96 of C).
// launch_bounds(256,2): grid caps us at 2 waves/SIMD anyway, so let VGPRs go
// to 256 -> the full a[4]+b[12] batch stays resident.
// In-loop barriers are lgkm-only: the 3-deep x-prefetch ring and the batched
// Wb loads stay in flight across iterations (no vmcnt(0) drain).
// Ring fix vs round 3: it+3 loads go into nc, shift na<-nb<-nc AFTER commit.
// ---------------------------------------------------------------------------
__global__ __launch_bounds__(256, 2)
void proj_rope_kernel(const float* __restrict__ x,
                      const _Float16* __restrict__ Wb,
                      _Float16* __restrict__ Qb,
                      _Float16* __restrict__ Ka,
                      _Float16* __restrict__ Va)
{
    const int r0   = blockIdx.x * 32;       // 32 | 2048: never straddles batch
    const int tid  = threadIdx.x;
    const int wave = tid >> 6;              // 0..3 = wave_n
    const int lane = tid & 63;
    const int half = lane >> 5;
    const int col  = lane & 31;

    __shared__ _Float16 Xb[2][2048];        // 4 blobs (kc) x 512 f16 per buf
    __shared__ _Float16 Out[32][136];       // epilogue transpose buffer

    f32x16 acc[3];
#pragma unroll
    for (int s = 0; s < 3; s++) acc[s] = (f32x16)0.f;

    // staging map: thread -> (row sr, f16-col c in {sc, sc+32})
    const int sr = tid >> 3;                // 0..31
    const int sc = (tid & 7) * 4;           // 0..28
    const float* __restrict__ xp = &x[(size_t)(r0 + sr) * EE + sc];
    // blob index for col c: (c>>4)*512 + (sr + 32*((c>>3)&1))*8 + (c&7)
    const int w0 = ((sc        >> 4) << 9) + ((sr + 32 * ((sc        >> 3) & 1)) << 3) + (sc & 7);
    const int w1 = (((sc + 32) >> 4) << 9) + ((sr + 32 * (((sc + 32) >> 3) & 1)) << 3) + (sc & 7);

    // 3-deep prefetch ring: iter0 committed pre-loop; na=iter1, nb=iter2
    float4 pa0 = *(const float4*)(xp);
    float4 pa1 = *(const float4*)(xp + 32);
    {   // pre-loop commit of iter 0 (no readers yet)
        f16x4 h0 = { (_Float16)pa0.x, (_Float16)pa0.y, (_Float16)pa0.z, (_Float16)pa0.w };
        f16x4 h1 = { (_Float16)pa1.x, (_Float16)pa1.y, (_Float16)pa1.z, (_Float16)pa1.w };
        *(f16x4*)&Xb[0][w0] = h0;
        *(f16x4*)&Xb[0][w1] = h1;
    }
    float4 na0 = *(const float4*)(xp + 64);
    float4 na1 = *(const float4*)(xp + 96);
    float4 nb0 = *(const float4*)(xp + 128);
    float4 nb1 = *(const float4*)(xp + 160);

    for (int it = 0; it < 16; it++) {
        const int buf = it & 1;
        BAR_LGKM();                         // Xb[buf] commits visible; no vm drain
        // batch-load all fragments (A from LDS, B from global frag-order Wb)
        f16x8 a[4], b[12];
#pragma unroll
        for (int kc = 0; kc < 4; kc++)
            a[kc] = *(f16x8*)&Xb[buf][(kc << 9) + lane * 8];
#pragma unroll
        for (int kc = 0; kc < 4; kc++)
#pragma unroll
            for (int s = 0; s < 3; s++)
                b[kc * 3 + s] = *(const f16x8*)&Wb[((size_t)(it * 4 + kc) * 12 + wave * 3 + s) * 512 + lane * 8];
        // issue iter it+3 x-loads early into nc: they ride under the MFMA
        // burst and across the next barriers (lgkm-only, never drained)
        float4 nc0, nc1;
        const bool have_nc = (it + 3 < 16);
        if (have_nc) {
            nc0 = *(const float4*)(xp + (it + 3) * 64);
            nc1 = *(const float4*)(xp + (it + 3) * 64 + 32);
        }
#pragma unroll
        for (int kc = 0; kc < 4; kc++)
#pragma unroll
            for (int s = 0; s < 3; s++)
                acc[s] = __builtin_amdgcn_mfma_f32_32x32x16_f16(a[kc], b[kc * 3 + s], acc[s], 0, 0, 0);
        // commit iter it+1 into the other buffer (its old readers done at barrier)
        if (it + 1 < 16) {
            f16x4 h0 = { (_Float16)na0.x, (_Float16)na0.y, (_Float16)na0.z, (_Float16)na0.w };
            f16x4 h1 = { (_Float16)na1.x, (_Float16)na1.y, (_Float16)na1.z, (_Float16)na1.w };
            *(f16x4*)&Xb[buf ^ 1][w0] = h0;
            *(f16x4*)&Xb[buf ^ 1][w1] = h1;
            na0 = nb0; na1 = nb1;           // ring shift AFTER commit
            if (have_nc) { nb0 = nc0; nb1 = nc1; }
        }
    }

    // ---- epilogue: RoPE + frag-layout stores via Out round-trip ----
    const int bidx = r0 >> 11;
    const int t0   = r0 & (TT - 1);

    for (int p = 0; p < 3; p++) {
        BAR_LGKM();
#pragma unroll
        for (int s = 0; s < 3; s++) {
            int gs = wave * 3 + s;          // 0..11 global 32-col subtile
            if ((gs >> 2) != p) continue;
            int dcol = (gs & 3) * 32 + col; // 0..127 within matrix p
            float f = 0.f;
            if (p < 2)
                f = __powf(10000.0f, -(float)(dcol & ~1) * (1.0f / 128.0f));
#pragma unroll
            for (int rg = 0; rg < 16; rg++) {
                int mrow = (rg & 3) + 8 * (rg >> 2) + 4 * half;
                float av = acc[s][rg];
                float res;
                if (p < 2) {
                    float ap = __shfl_xor(av, 1);   // RoPE pair partner (dcol^1)
                    float sa, ca;
                    __sincosf((float)(t0 + mrow) * f, &sa, &ca);
                    res = av * ca + ap * ((dcol & 1) ? sa : -sa);
                    if (p == 0) res *= QSCALE;
                } else {
                    res = av;
                }
                Out[mrow][dcol] = (_Float16)res;
            }
        }
        BAR_LGKM();
        if (p < 2) {
            _Float16* __restrict__ dst = (p == 0) ? Qb : Ka;
#pragma unroll
            for (int jj = 0; jj < 2; jj++) {
                int cid = tid + 256 * jj;   // 0..511 = 8 kc x 64 lanes
                int kc = cid >> 6, ln = cid & 63;
                f16x8 v8 = *(f16x8*)&Out[ln & 31][kc * 16 + (ln >> 5) * 8];
                size_t ga = ((((size_t)bidx * 64 + (t0 >> 5)) * 8 + kc) * 64 + ln) * 8;
                *(f16x8*)&dst[ga] = v8;
            }
        } else {
#pragma unroll
            for (int jj = 0; jj < 2; jj++) {
                int cid = tid + 256 * jj;   // 0..511 = 2 key-chunks x 4 ds x 64 lanes
                int kcl = cid >> 8, ds = (cid >> 6) & 3, ln = cid & 63;
                f16x8 vv;
#pragma unroll
                for (int e = 0; e < 8; e++)
                    vv[e] = Out[kcl * 16 + (ln >> 5) * 8 + e][ds * 32 + (ln & 31)];
                size_t ga = ((((size_t)bidx * 128 + (t0 >> 4) + kcl) * 4 + ds) * 64 + ln) * 8;
                *(f16x8*)&Va[ga] = vv;
            }
        }
    }
}

// ---------------------------------------------------------------------------
// Kernel 2: MFMA flash attention.  Q-tile 128 (4 waves), K-tile 64, split-K
// chunks of exactly 2 tiles -> grid (136, 8), perfectly uniform work.
// K/V reg-prefetched then LDS-staged; lgkm-only barriers keep the next-tile
// global loads in flight across the whole compute phase.
// ---------------------------------------------------------------------------
__global__ __launch_bounds__(256, 2)
void attn_kernel(const _Float16* __restrict__ Qb,
                 const _Float16* __restrict__ Ka,
                 const _Float16* __restrict__ Va,
                 _Float16* __restrict__ opart,
                 float* __restrict__ mpart,
                 float* __restrict__ lpart)
{
    const int b = blockIdx.y;
    // triangular inversion: v = xt(xt+1)/2 + c, c in [0, xt]
    int xt = 15, c = 0;
    {
        int v = blockIdx.x, s0 = 0;
        for (int j = 0; j < 16; j++) {
            if (v < s0 + j + 1) { xt = j; c = v - s0; break; }
            s0 += j + 1;
        }
    }
    const int q0  = xt * 128;
    const int kt0 = 2 * c;                  // this block's 2 key-tiles

    const int tid  = threadIdx.x;
    const int wave = tid >> 6;
    const int lane = tid & 63;
    const int half = lane >> 5;
    const int col  = lane & 31;

    __shared__ _Float16 Kb[8192];           // 16 blobs (g*8+kc) x 512 f16
    __shared__ _Float16 Vb[8192];           // 16 blobs (kcl*4+ds) x 512 f16
    __shared__ _Float16 Ps[4][32][72];      // [wave][q][key] — same-wave only

    const _Float16* __restrict__ kst = Ka + (size_t)b * 64 * 4096;
    const _Float16* __restrict__ vst = Va + (size_t)b * 128 * 2048;

    // issue first-tile loads before anything else (max latency cover)
    f16x8 kr[4], vr[4];
    {
        const _Float16* kp = kst + (size_t)kt0 * 8192;
        const _Float16* vp = vst + (size_t)kt0 * 8192;
#pragma unroll
        for (int i = 0; i < 4; i++) kr[i] = *(const f16x8*)&kp[(tid + 256 * i) * 8];
#pragma unroll
        for (int i = 0; i < 4; i++) vr[i] = *(const f16x8*)&vp[(tid + 256 * i) * 8];
    }

    const int qg = q0 + wave * 32 + col;    // this lane's query
    f16x8 qb[8];
#pragma unroll
    for (int kc = 0; kc < 8; kc++)
        qb[kc] = *(const f16x8*)&Qb[((((size_t)b * 64 + xt * 4 + wave) * 8 + kc) * 64 + lane) * 8];

    f32x16 Of[4];
#pragma unroll
    for (int t = 0; t < 4; t++) Of[t] = (f32x16)0.f;
    float m_ = -1e30f, l_ = 0.f;

#pragma unroll
    for (int tt = 0; tt < 2; tt++) {
        const int kt  = kt0 + tt;
        const int kb0 = kt * 64;
        BAR_LGKM();                         // prev compute done reading LDS
#pragma unroll
        for (int i = 0; i < 4; i++) *(f16x8*)&Kb[(tid + 256 * i) * 8] = kr[i];
#pragma unroll
        for (int i = 0; i < 4; i++) *(f16x8*)&Vb[(tid + 256 * i) * 8] = vr[i];
        BAR_LGKM();                         // staging visible
        if (tt == 0) {                      // issue next-tile loads now; they
            const _Float16* kp = kst + (size_t)(kt0 + 1) * 8192;    // stay in
            const _Float16* vp = vst + (size_t)(kt0 + 1) * 8192;    // flight
#pragma unroll
            for (int i = 0; i < 4; i++) kr[i] = *(const f16x8*)&kp[(tid + 256 * i) * 8];
#pragma unroll
            for (int i = 0; i < 4; i++) vr[i] = *(const f16x8*)&vp[(tid + 256 * i) * 8];
        }

        // ---- S^T = K Q^T : rows = keys, cols = queries ----
        f32x16 sf[2];
#pragma unroll
        for (int g = 0; g < 2; g++) {
            sf[g] = (f32x16)0.f;
#pragma unroll
            for (int kc = 0; kc < 8; kc++) {
                f16x8 kf = *(f16x8*)&Kb[((g * 8 + kc) * 64 + lane) * 8];
                sf[g] = __builtin_amdgcn_mfma_f32_32x32x16_f16(kf, qb[kc], sf[g], 0, 0, 0);
            }
        }

        // ---- softmax: 32 key-scores in-lane, one shfl step (xor 32) ----
        const bool diag = (kt >= 2 * xt);
        float mloc = -1e30f;
#pragma unroll
        for (int g = 0; g < 2; g++)
#pragma unroll
            for (int rg = 0; rg < 16; rg++) {
                int key = kb0 + g * 32 + (rg & 3) + 8 * (rg >> 2) + 4 * half;
                float val = sf[g][rg];
                val = (!diag || key <= qg) ? val : -1e30f;
                sf[g][rg] = val;
                mloc = fmaxf(mloc, val);
            }
        mloc = fmaxf(mloc, __shfl_xor(mloc, 32));
        float mnew  = fmaxf(m_, mloc);
        float alpha = __builtin_amdgcn_exp2f(m_ - mnew);
        float ps = 0.f;
#pragma unroll
        for (int g = 0; g < 2; g++) {
#pragma unroll
            for (int rc = 0; rc < 4; rc++) {
                f16x4 p4;
#pragma unroll
                for (int rr = 0; rr < 4; rr++) {
                    float p = __builtin_amdgcn_exp2f(sf[g][4 * rc + rr] - mnew);
                    ps += p;
                    p4[rr] = (_Float16)p;
                }
                *(f16x4*)&Ps[wave][col][g * 32 + 8 * rc + 4 * half] = p4;
            }
        }
        ps += __shfl_xor(ps, 32);
        l_ = l_ * alpha + ps;
        m_ = mnew;
#pragma unroll
        for (int t = 0; t < 4; t++) Of[t] *= alpha;

        // ---- O^T += V^T P^T (P via same-wave LDS round-trip) ----
        f16x8 pb[4];
#pragma unroll
        for (int kc = 0; kc < 4; kc++)
            pb[kc] = *(f16x8*)&Ps[wave][col][kc * 16 + half * 8];
#pragma unroll
        for (int t = 0; t < 4; t++) {
#pragma unroll
            for (int kcl = 0; kcl < 4; kcl++) {
                f16x8 vf = *(f16x8*)&Vb[((kcl * 4 + t) * 64 + lane) * 8];
                Of[t] = __builtin_amdgcn_mfma_f32_32x32x16_f16(vf, pb[kcl], Of[t], 0, 0, 0);
            }
        }
    }

    // ---- partial store (f16 unnormalized O^T -> [q][d], f32 m/l) ----
    const int slot = (b * 16 + xt) * 16 + c;
    _Float16* op = opart + ((size_t)slot * 128 + wave * 32 + col) * DD;
#pragma unroll
    for (int t = 0; t < 4; t++) {
#pragma unroll
        for (int rc = 0; rc < 4; rc++) {
            f16x4 o4 = { (_Float16)Of[t][4 * rc + 0], (_Float16)Of[t][4 * rc + 1],
                         (_Float16)Of[t][4 * rc + 2], (_Float16)Of[t][4 * rc + 3] };
            *(f16x4*)&op[t * 32 + 8 * rc + 4 * half] = o4;
        }
    }
    if (half == 0) {
        mpart[slot * 128 + wave * 32 + col] = m_;
        lpart[slot * 128 + wave * 32 + col] = l_;
    }
}

// ---------------------------------------------------------------------------
// Kernel 3: combine up to 16 split-K partials per query row.
// ---------------------------------------------------------------------------
__global__ __launch_bounds__(256)
void combine_kernel(const _Float16* __restrict__ opart,
                    const float* __restrict__ mpart,
                    const float* __restrict__ lpart,
                    float* __restrict__ out)
{
    int gid = blockIdx.x * 256 + threadIdx.x;   // 0..2M-1
    int d   = gid & 127;
    int t   = gid >> 7;                         // 0..16383
    int b   = t >> 11;
    int tl  = t & (TT - 1);
    int xt  = tl >> 7;
    int rl  = tl & 127;
    int np  = xt + 1;                           // chunks of 2 tiles each
    int sb  = (b * 16 + xt) * 16;

    float mm = -1e30f;
    for (int j = 0; j < np; j++)
        mm = fmaxf(mm, mpart[(sb + j) * 128 + rl]);
    float acc = 0.f, den = 0.f;
    for (int j = 0; j < np; j++) {
        float w = __builtin_amdgcn_exp2f(mpart[(sb + j) * 128 + rl] - mm);
        den += w * lpart[(sb + j) * 128 + rl];
        acc += w * (float)opart[((size_t)(sb + j) * 128 + rl) * DD + d];
    }
    out[gid] = acc / den;
}

extern "C" void kernel_launch(void* const* d_in, const int* in_sizes, int n_in,
                              void* d_out, int out_size, void* d_ws, size_t ws_size,
                              hipStream_t stream)
{
    const float* x  = (const float*)d_in[0];
    const float* Wq = (const float*)d_in[1];
    const float* Wk = (const float*)d_in[2];
    const float* Wv = (const float*)d_in[3];
    float* out = (float*)d_out;

    const size_t NTOK = (size_t)BB * TT;        // 16384
    _Float16* Qb = (_Float16*)d_ws;             // 4 MB
    _Float16* Ka = Qb + NTOK * DD;              // 4 MB
    _Float16* Va = Ka + NTOK * DD;              // 4 MB
    _Float16* Wb = Va + NTOK * DD;              // 0.75 MB
    _Float16* opart = Wb + (size_t)384 * EE;    // 64 MB (2048 slots x 128 x 128)
    float* mp = (float*)(opart + (size_t)2048 * 128 * DD);  // 1 MB
    float* lp = mp + 2048 * 128;                // 1 MB

    wt_prep_kernel<<<dim3(192), dim3(256), 0, stream>>>(Wq, Wk, Wv, Wb);
    proj_rope_kernel<<<dim3(512), dim3(256), 0, stream>>>(x, Wb, Qb, Ka, Va);
    attn_kernel<<<dim3(136, BB), dim3(256), 0, stream>>>(Qb, Ka, Va, opart, mp, lp);
    combine_kernel<<<dim3((int)(NTOK * DD / 256)), dim3(256), 0, stream>>>(opart, mp, lp, out);
}